// Round 10
// baseline (203.480 us; speedup 1.0000x reference)
//
#include <hip/hip_runtime.h>

// Shapes
#define NB   256      // batch
#define E0   300      // embedding
#define EP   304      // padded embedding
#define F_   512      // features
#define KP   1536     // padded K (5*304=1520 -> 24 K-tiles of 64)
#define NKT2 24       // K-tiles of 64
#define LQ_  64
#define LA_  256

typedef __attribute__((ext_vector_type(4))) float f32x4;
typedef __attribute__((ext_vector_type(8))) short short8;

#define XQ_ELEMS (NB * (LQ_ + 4) * EP)   // 5,292,032
#define XA_ELEMS (NB * (LA_ + 4) * EP)   // 20,234,240
#define WT_ELEMS (F_ * KP)               // 786,432 (row-major)
#define OUTQ_ELEMS ((size_t)NB * F_ * LQ_)
#define XROWS (NB * (LQ_ + 4) + NB * (LA_ + 4))   // 83,968

__device__ __forceinline__ unsigned short f2bf(float x) {
    unsigned int u = __float_as_uint(x);
    u = u + 0x7fffu + ((u >> 16) & 1u);   // RNE
    return (unsigned short)(u >> 16);
}

// Zero-padded bf16 x with halo, flat-indexed dense blocks. (Verified r6-r9.)
__global__ void prep_x(const float* __restrict__ q, const float* __restrict__ a,
                       unsigned short* __restrict__ xq, unsigned short* __restrict__ xa)
{
    int idx = blockIdx.x * 256 + threadIdx.x;
    if (idx >= XROWS * 76) return;
    int row = idx / 76;
    int col = idx - row * 76;

    const float* src;
    unsigned short* dst;
    bool valid;
    if (row < NB * (LQ_ + 4)) {
        int b = row / (LQ_ + 4), lp = row - b * (LQ_ + 4);
        dst = xq + (size_t)row * EP;
        valid = (lp >= 2 && lp < 2 + LQ_);
        src = q + ((size_t)b * LQ_ + (lp - 2)) * E0;
    } else {
        int r2 = row - NB * (LQ_ + 4);
        int b = r2 / (LA_ + 4), lp = r2 - b * (LA_ + 4);
        dst = xa + (size_t)r2 * EP;
        valid = (lp >= 2 && lp < 2 + LA_);
        src = a + ((size_t)b * LA_ + (lp - 2)) * E0;
    }
    unsigned long long pk = 0ull;
    if (valid && col < 75) {
        const float4 v = reinterpret_cast<const float4*>(src)[col];
        pk = (unsigned long long)f2bf(v.x)
           | ((unsigned long long)f2bf(v.y) << 16)
           | ((unsigned long long)f2bf(v.z) << 32)
           | ((unsigned long long)f2bf(v.w) << 48);
    }
    *reinterpret_cast<unsigned long long*>(dst + (size_t)col * 4) = pk;
}

// Row-major Wt[f][k']: k'=j*304+e (e<300), else 0.  (Verified r1-r3.)
__global__ void prep_w(const float* __restrict__ W, unsigned short* __restrict__ wt)
{
    int idx = blockIdx.x * 256 + threadIdx.x;      // grid = F_*KP/256
    int f = idx / KP;
    int k = idx - f * KP;
    int j = k / EP;
    int e = k - j * EP;
    float v = (k < 5 * EP && e < E0) ? W[(size_t)(j * E0 + e) * F_ + f] : 0.f;
    wt[idx] = f2bf(v);
}

// m201-template port: 256f x 256l tile, BK=64, 8 waves (2f x 4l), per-wave
// 128f x 64l (acc[8][4]).  LDS 128 KB: 2 bufs x [ W 256x64 | Z 256x64 ] bf16.
// Per K-tile kt: 4 phases, each {ds_read subtile + stage 1 half-tile (2 GLLDS)
// -> barrier + lgkmcnt(0) + sched_barrier -> setprio(1) 16 MFMA setprio(0) ->
// barrier}.  ONE vmcnt fence per K-tile (end-ph3), steady vmcnt(6).
// Stage units (8 KB = 2 GLLDS each): WQ02 = W rows {0-63,128-191} both kk;
// WQ13 = +64; ZE = Z rows {0,64,128,192}+0..31; ZO = +32.  These equal the
// block-wide read-completion sets: ph0 reads A(m0-3)=WQ02-rows + B(n0-1)=ZE-
// rows; ph1 reads B(n2-3)=ZO; ph2 reads A(m4-7)=WQ13; so a unit staged at the
// NEXT phase never overwrites unread data (all phase reads lgkm-drain before
// that phase's closing barrier).  Issue schedule (per wave, in-order):
//   kt.ph0: WQ13(kt+1)->bufN | kt.ph1: WQ02(kt+2)->bufC | kt.ph2: ZE(kt+2)
//   | kt.ph3: ZO(kt+2).
// Ledger: at F(kt) (end-ph3) outstanding = 7 units (from kt-1.ph1 .. kt.ph3);
// vmcnt(6) retires oldest 4 = all of K-tile kt+1 -> phases of kt+1 read safely;
// 3 units (kt+2's WQ02/ZE/ZO) stay in flight.  Prologue: 7 units then vmcnt(6)
// establishes the same invariant.  Tail: F(22)=vmcnt(0), F(23) skipped.
__global__ __launch_bounds__(512, 1) void qa_gemm(
    const unsigned short* __restrict__ xq,
    const unsigned short* __restrict__ xa,
    const unsigned short* __restrict__ wt,
    const float* __restrict__ bias,
    float* __restrict__ out)
{
    __shared__ __align__(16) unsigned short lds[2 * 32768];   // 128 KB

    const int bid = blockIdx.x;
    const int wg  = (bid & 7) * 80 + (bid >> 3);   // XCD swizzle, 640 % 8 == 0

    const unsigned short* xp;
    float* ob;
    int Mbase, lsh, Lp, ftBase;
    if (wg < 128) {                 // question: 64 l-tiles x 2 f-tiles
        Mbase  = (wg >> 1) * 256;
        ftBase = (wg & 1) * 256;
        xp = xq; lsh = 6; Lp = LQ_ + 4;
        ob = out;
    } else {                        // answer: 256 l-tiles x 2 f-tiles
        const int id = wg - 128;
        Mbase  = (id >> 1) * 256;
        ftBase = (id & 1) * 256;
        xp = xa; lsh = 8; Lp = LA_ + 4;
        ob = out + OUTQ_ELEMS;
    }
    const int Lv = 1 << lsh;

    const int tid  = threadIdx.x;
    const int lane = tid & 63;
    const int wid  = tid >> 6;
    const int wf   = wid >> 2;      // f half (128 rows)
    const int wn   = wid & 3;       // l quarter (64 rows)
    const int lq   = lane >> 4;
    const int lr   = lane & 15;
    const int s_c  = (lane & 3) ^ ((lane >> 3) & 3);   // pre-swizzled src chunk
    const int sub  = lane >> 2;

    // ---- stage geometry (16 rows x 32 k per wave-instruction; verified r1-r9)
    const int wrow = (wid < 4) ? wid * 16 : (wid - 4) * 16 + 128;   // WQ02 slice
    const unsigned short* wsrc = wt + (size_t)(ftBase + wrow + sub) * KP + s_c * 8;
    const int zrow = (wid >> 1) * 64 + (wid & 1) * 16;              // ZE slice
    const int mE = Mbase + zrow + sub, mO = mE + 32;
    const unsigned short* zsrcE = xp + (size_t)((mE >> lsh) * Lp + (mE & (Lv - 1))) * EP + s_c * 8;
    const unsigned short* zsrcO = xp + (size_t)((mO >> lsh) * Lp + (mO & (Lv - 1))) * EP + s_c * 8;
    const int wdst  = wrow * 32;            // shorts, within W region of a buf
    const int zdstE = 16384 + zrow * 32;    // shorts, Z region starts at 16384

#define GLLDS(p, d) __builtin_amdgcn_global_load_lds(                               \
        (const __attribute__((address_space(1))) void*)(p),                         \
        (__attribute__((address_space(3))) void*)(d), 16, 0, 0)
// Each ST_* = one half-tile = 2 GLLDS (kk0 block, kk1 block = +8192 shorts).
#define ST_W(BUF, T, Q) do {                                                        \
    const unsigned short* s_ = wsrc + (size_t)(T) * 64 + (size_t)(Q) * 64 * KP;     \
    GLLDS(s_,      lds + (BUF) + wdst + (Q) * 2048);                                \
    GLLDS(s_ + 32, lds + (BUF) + 8192 + wdst + (Q) * 2048); } while (0)
#define ST_ZE(BUF, T) do {                                                          \
    const unsigned short* s_ = zsrcE + (size_t)(T) * 64;                            \
    GLLDS(s_,      lds + (BUF) + zdstE);                                            \
    GLLDS(s_ + 32, lds + (BUF) + 8192 + zdstE); } while (0)
#define ST_ZO(BUF, T) do {                                                          \
    const unsigned short* s_ = zsrcO + (size_t)(T) * 64;                            \
    GLLDS(s_,      lds + (BUF) + zdstE + 1024);                                     \
    GLLDS(s_ + 32, lds + (BUF) + 8192 + zdstE + 1024); } while (0)

    // ---- fragment read offsets (bytes within a buf), chunk-swizzled (verified)
    const int cs = (lq ^ ((lr >> 1) & 3)) * 16;
    int aoff[8], boff[8];
#pragma unroll
    for (int m = 0; m < 4; ++m)
#pragma unroll
        for (int kk = 0; kk < 2; ++kk)
            aoff[m * 2 + kk] = kk * 16384 + (wf * 128 + m * 16 + lr) * 64 + cs;
#pragma unroll
    for (int n = 0; n < 4; ++n)
#pragma unroll
        for (int kk = 0; kk < 2; ++kk)
            boff[n * 2 + kk] = 32768 + kk * 16384 + (wn * 64 + n * 16 + lr) * 64 + cs;

    f32x4 acc[8][4] = {};
    short8 a4[8], bA[4], bB[4];

#define MFMA(a, b, c) __builtin_amdgcn_mfma_f32_16x16x32_bf16((a), (b), (c), 0, 0, 0)
#define RD_A(OFS) do { _Pragma("unroll") for (int i = 0; i < 8; ++i)                \
    a4[i] = *(const short8*)(bb + aoff[i] + (OFS)); } while (0)
#define RD_B(DST, B0) do { _Pragma("unroll") for (int j = 0; j < 4; ++j)            \
    DST[j] = *(const short8*)(bb + boff[(B0) + j]); } while (0)
#define MFMA_Q(MB, NBASE, BV) do {                                                  \
    _Pragma("unroll") for (int m = 0; m < 4; ++m)                                   \
    _Pragma("unroll") for (int n = 0; n < 2; ++n) {                                 \
        acc[(MB) + m][(NBASE) + n] = MFMA(a4[m * 2 + 0], BV[n * 2 + 0], acc[(MB) + m][(NBASE) + n]); \
        acc[(MB) + m][(NBASE) + n] = MFMA(a4[m * 2 + 1], BV[n * 2 + 1], acc[(MB) + m][(NBASE) + n]); \
    } } while (0)
#define PH_SYNC do { asm volatile("s_barrier\n\ts_waitcnt lgkmcnt(0)" ::: "memory"); \
    __builtin_amdgcn_sched_barrier(0); } while (0)
#define PH_END do { __builtin_amdgcn_sched_barrier(0);                              \
    asm volatile("s_barrier" ::: "memory"); } while (0)
#define SP1 __builtin_amdgcn_s_setprio(1)
#define SP0 __builtin_amdgcn_s_setprio(0)

    // Prologue: 7 units in order [WQ02(0),ZE(0),ZO(0),WQ13(0),WQ02(1),ZE(1),ZO(1)]
    ST_W(0, 0, 0); ST_ZE(0, 0); ST_ZO(0, 0); ST_W(0, 0, 1);
    ST_W(32768, 1, 0); ST_ZE(32768, 1); ST_ZO(32768, 1);
    asm volatile("s_waitcnt vmcnt(6)\n\ts_barrier" ::: "memory");

    for (int kt = 0; kt < 22; ++kt) {
        const int cur = (kt & 1) * 32768;       // shorts
        const int nxt = 32768 - cur;
        const char* bb = (const char*)lds + cur * 2;
        // ph0
        RD_A(0); RD_B(bA, 0);
        ST_W(nxt, kt + 1, 1);
        PH_SYNC; SP1; MFMA_Q(0, 0, bA); SP0; PH_END;
        // ph1
        RD_B(bB, 4);
        ST_W(cur, kt + 2, 0);
        PH_SYNC; SP1; MFMA_Q(0, 2, bB); SP0; PH_END;
        // ph2
        RD_A(4096);
        ST_ZE(cur, kt + 2);
        PH_SYNC; SP1; MFMA_Q(4, 0, bA); SP0; PH_END;
        // ph3 (+ the K-tile fence)
        ST_ZO(cur, kt + 2);
        PH_SYNC; SP1; MFMA_Q(4, 2, bB); SP0;
        __builtin_amdgcn_sched_barrier(0);
        asm volatile("s_waitcnt vmcnt(6)\n\ts_barrier" ::: "memory");
    }
    {   // kt = 22 (cur buf 0): only stage left is WQ13(23); F = vmcnt(0)
        const char* bb = (const char*)lds;
        RD_A(0); RD_B(bA, 0); ST_W(32768, 23, 1);
        PH_SYNC; SP1; MFMA_Q(0, 0, bA); SP0; PH_END;
        RD_B(bB, 4);
        PH_SYNC; SP1; MFMA_Q(0, 2, bB); SP0; PH_END;
        RD_A(4096);
        PH_SYNC; SP1; MFMA_Q(4, 0, bA); SP0; PH_END;
        PH_SYNC; SP1; MFMA_Q(4, 2, bB); SP0;
        __builtin_amdgcn_sched_barrier(0);
        asm volatile("s_waitcnt vmcnt(0)\n\ts_barrier" ::: "memory");
    }
    {   // kt = 23 (cur buf 1): no stages, no fence
        const char* bb = (const char*)lds + 65536;
        RD_A(0); RD_B(bA, 0);
        PH_SYNC; SP1; MFMA_Q(0, 0, bA); SP0; PH_END;
        RD_B(bB, 4);
        PH_SYNC; SP1; MFMA_Q(0, 2, bB); SP0; PH_END;
        RD_A(4096);
        PH_SYNC; SP1; MFMA_Q(4, 0, bA); SP0; PH_END;
        PH_SYNC; SP1; MFMA_Q(4, 2, bB); SP0;
        __builtin_amdgcn_sched_barrier(0);
    }

#undef PH_SYNC
#undef PH_END
#undef MFMA_Q
#undef RD_A
#undef RD_B
#undef ST_W
#undef ST_ZE
#undef ST_ZO
#undef GLLDS
#undef MFMA

    // ---- epilogue: D row = f = lq*4+reg, col = l = lr (verified r1-r9; r2 shape)
#pragma unroll
    for (int ns = 0; ns < 4; ++ns) {
        const int m = Mbase + wn * 64 + ns * 16 + lr;
        const int b = m >> lsh;
        const int l = m & (Lv - 1);
        float* orow = ob + ((size_t)b * F_ << lsh) + l;
#pragma unroll
        for (int ms = 0; ms < 8; ++ms) {
            const int f0 = ftBase + wf * 128 + ms * 16 + lq * 4;
            const f32x4 v = acc[ms][ns];
#pragma unroll
            for (int r = 0; r < 4; ++r)
                orow[(size_t)(f0 + r) << lsh] = v[r] + __ldg(&bias[f0 + r]);
        }
    }
}

extern "C" void kernel_launch(void* const* d_in, const int* in_sizes, int n_in,
                              void* d_out, int out_size, void* d_ws, size_t ws_size,
                              hipStream_t stream)
{
    const float* q    = (const float*)d_in[0];
    const float* a    = (const float*)d_in[1];
    const float* W    = (const float*)d_in[2];
    const float* bias = (const float*)d_in[3];
    float* out = (float*)d_out;

    unsigned short* xq = (unsigned short*)d_ws;
    unsigned short* xa = xq + XQ_ELEMS;
    unsigned short* wt = xa + XA_ELEMS;
    // ws needed: (XQ+XA+WT)*2 = 52.6 MB
    // (xa K-pad tail reads overrun <=32 B into wt: in-bounds; matching Wt
    //  columns are zero, so the values are don't-care.)

    prep_x<<<(XROWS * 76 + 255) / 256, 256, 0, stream>>>(q, a, xq, xa);
    prep_w<<<WT_ELEMS / 256, 256, 0, stream>>>(W, wt);
    qa_gemm<<<640, 512, 0, stream>>>(xq, xa, wt, bias, out);
}